// Round 4
// baseline (2746.574 us; speedup 1.0000x reference)
//
#include <hip/hip_runtime.h>
#include <math.h>
#include <string.h>

// ---------------- problem constants ----------------
#define E_EDGES 40000
#define N_NODES 80000
#define NE 4          // edges per block

// ---- sign knobs (verified correct in round 1) ----
#define S111 1.0
#define S122 1.0
#define S212 1.0
#define S221 1.0
#define S222 1.0

struct W3J { float v[615]; };

// ---------------- host: build W3J tensors (verified round 1) ----------------
static void build_w3j(W3J& w) {
    const double s3 = sqrt(3.0), s5 = sqrt(5.0), s15 = sqrt(15.0);
    struct Mono { int a, b, c; double co; };
    Mono Y[3][5][3]; int nm[3][5];
    for (int l = 0; l < 3; l++) for (int c = 0; c < 5; c++) nm[l][c] = 0;
    nm[0][0] = 1; Y[0][0][0] = Mono{0,0,0,1.0};
    nm[1][0] = 1; Y[1][0][0] = Mono{1,0,0,s3};
    nm[1][1] = 1; Y[1][1][0] = Mono{0,1,0,s3};
    nm[1][2] = 1; Y[1][2][0] = Mono{0,0,1,s3};
    nm[2][0] = 1; Y[2][0][0] = Mono{1,0,1,s15};
    nm[2][1] = 1; Y[2][1][0] = Mono{1,1,0,s15};
    nm[2][2] = 3; Y[2][2][0] = Mono{0,2,0,s5};  Y[2][2][1] = Mono{2,0,0,-0.5*s5}; Y[2][2][2] = Mono{0,0,2,-0.5*s5};
    nm[2][3] = 1; Y[2][3][0] = Mono{0,1,1,s15};
    nm[2][4] = 2; Y[2][4][0] = Mono{0,0,2,0.5*s15}; Y[2][4][1] = Mono{2,0,0,-0.5*s15};

    static const int PL[15][3] = {{0,0,0},{0,1,1},{0,2,2},{1,0,1},{1,1,0},{1,1,1},{1,1,2},{1,2,1},
                                  {1,2,2},{2,0,2},{2,1,1},{2,1,2},{2,2,0},{2,2,1},{2,2,2}};
    static const int OFF[15]  = {0,1,10,35,44,53,80,125,170,245,270,315,390,415,490};
    static const int ANCH[15] = {0,0,0,0,0,5,22,22,29,0,22,9,0,13,2};
    const double ASGN[15] = {1,1,1,1,1, S111, 1,1, S122, 1,1, S212, 1, S221, S222};

    auto dfact = [](int n) { double r = 1.0; for (int k = n; k > 1; k -= 2) r *= k; return r; };

    double Mm[5][3][3]; memset(Mm, 0, sizeof(Mm));
    const double mh = s15 * 0.5;
    Mm[0][0][2] = Mm[0][2][0] = mh;
    Mm[1][0][1] = Mm[1][1][0] = mh;
    Mm[2][0][0] = -0.5*s5; Mm[2][1][1] = s5; Mm[2][2][2] = -0.5*s5;
    Mm[3][1][2] = Mm[3][2][1] = mh;
    Mm[4][0][0] = -mh; Mm[4][2][2] = mh;
    double T[3][5][5];
    for (int a = 0; a < 5; a++) for (int b = 0; b < 5; b++) {
        double K[3][3];
        for (int i = 0; i < 3; i++) for (int j = 0; j < 3; j++) {
            double ab = 0, ba = 0;
            for (int r = 0; r < 3; r++) { ab += Mm[a][i][r]*Mm[b][r][j]; ba += Mm[b][i][r]*Mm[a][r][j]; }
            K[i][j] = ab - ba;
        }
        T[0][a][b] = K[1][2]; T[1][a][b] = K[2][0]; T[2][a][b] = K[0][1];
    }

    for (int p = 0; p < 15; p++) {
        int l1 = PL[p][0], l2 = PL[p][1], l3 = PL[p][2];
        int d1 = 2*l1+1, d2 = 2*l2+1, d3 = 2*l3+1, d = d1*d2*d3;
        double tt[125];
        if (((l1 + l2 + l3) & 1) == 0) {
            for (int i = 0; i < d1; i++) for (int j = 0; j < d2; j++) for (int k = 0; k < d3; k++) {
                double a = 0;
                for (int q1 = 0; q1 < nm[l1][i]; q1++)
                for (int q2 = 0; q2 < nm[l2][j]; q2++)
                for (int q3 = 0; q3 < nm[l3][k]; q3++) {
                    const Mono& A = Y[l1][i][q1]; const Mono& B = Y[l2][j][q2]; const Mono& C = Y[l3][k][q3];
                    int xa = A.a+B.a+C.a, yb = A.b+B.b+C.b, zc = A.c+B.c+C.c;
                    if ((xa & 1) || (yb & 1) || (zc & 1)) continue;
                    a += A.co*B.co*C.co * dfact(xa-1)*dfact(yb-1)*dfact(zc-1) / dfact(xa+yb+zc+1);
                }
                tt[(i*d2 + j)*d3 + k] = a;
            }
        } else if (p == 5) {
            for (int q = 0; q < 27; q++) tt[q] = 0;
            tt[0*9+1*3+2] = 1; tt[1*9+2*3+0] = 1; tt[2*9+0*3+1] = 1;
            tt[0*9+2*3+1] = -1; tt[1*9+0*3+2] = -1; tt[2*9+1*3+0] = -1;
        } else {
            for (int q = 0; q < d; q++) tt[q] = 0;
            if (p == 8)  for (int i=0;i<3;i++) for(int a=0;a<5;a++) for(int b=0;b<5;b++) tt[(i*5+a)*5+b] = T[i][a][b];
            if (p == 11) for (int a=0;a<5;a++) for(int i=0;i<3;i++) for(int b=0;b<5;b++) tt[(a*3+i)*5+b] = T[i][a][b];
            if (p == 13) for (int a=0;a<5;a++) for(int b=0;b<5;b++) for(int i=0;i<3;i++) tt[(a*5+b)*3+i] = T[i][a][b];
        }
        double nrm = 0; for (int q = 0; q < d; q++) nrm += tt[q]*tt[q];
        nrm = sqrt(nrm);
        double sg = ((tt[ANCH[p]] >= 0) ? 1.0 : -1.0) * ASGN[p] / nrm;
        for (int q = 0; q < d; q++) w.v[OFF[p] + q] = (float)(tt[q] * sg);
    }
}

// ---------------- device tables (runtime-indexed, ck phase only) ----------------
__device__ const int d_L2r[15]    = {0,1,2,0,1,1,1,2,2,0,1,1,2,2,2};
__device__ const int d_L3r[15]    = {0,1,2,1,0,1,2,1,2,2,1,2,0,1,2};
__device__ const int d_OFFr[15]   = {0,1,10,35,44,53,80,125,170,245,270,315,390,415,490};
__device__ const int d_CKOFFr[15] = {0,1,4,9,18,21,30,45,54,69,94,109,134,139,154};
__device__ const int d_SLOr[3]    = {0,1,4};

#define S_H  0.1414213562373095f    // 1/sqrt(50)
#define S_CS 0.13065629648763766f   // cos(pi/8)/sqrt(50)
#define S_L2 0.03826834323650898f   // sin(pi/8)/10

// packed-weight layout in d_ws (floats)
#define WS_WP3 0         // [3][50][50][8] {wlin1 l0..2, wsc l0..2, pad, pad}
#define WS_W6P 60000     // [3][50][50][4] {wlin2 l0..2, pad}
#define WS_W2T 90000     // [3][750][100]  W2 transposed
#define WS_WGT 315000    // [3][50][52]    Wgate transposed (pad 52)
#define WS_W1T 322800    // [3][100][12]   W1 transposed (pad 12)
#define WS_TOTAL 326400

__device__ __forceinline__ float sigf(float a) { return 1.0f / (1.0f + expf(-a)); }

// ---------------- one-time weight repack ----------------
__global__ void k_pack(const float* __restrict__ Wsc, const float* __restrict__ Wlin1,
                       const float* __restrict__ Wlin2, const float* __restrict__ Wgate,
                       const float* __restrict__ W2, const float* __restrict__ W1,
                       float* __restrict__ ws) {
    for (int i = blockIdx.x*blockDim.x + threadIdx.x; i < WS_TOTAL; i += gridDim.x*blockDim.x) {
        float val = 0.0f;
        if (i < WS_W6P) {
            int c = i & 7, r = i >> 3; int u = r % 50, v = (r/50) % 50, L = r/2500;
            if (c < 3) val = Wlin1[L*7500 + c*2500 + u*50 + v];
            else if (c < 6) val = Wsc[L*7500 + (c-3)*2500 + u*50 + v];
        } else if (i < WS_W2T) {
            int q = i - WS_W6P; int c = q & 3, r = q >> 2; int u = r%50, v = (r/50)%50, L = r/2500;
            if (c < 3) val = Wlin2[L*7500 + c*2500 + u*50 + v];
        } else if (i < WS_WGT) {
            int q = i - WS_W2T; int j = q % 100, o = (q/100)%750, L = q/75000;
            val = W2[L*75000 + j*750 + o];
        } else if (i < WS_W1T) {
            int q = i - WS_WGT; int u = q % 52, v = (q/52)%50, L = q/2600;
            if (u < 50) val = Wgate[L*2500 + u*50 + v];
        } else {
            int q = i - WS_W1T; int b = q % 12, j = (q/12)%100, L = q/1200;
            if (b < 10) val = W1[L*1000 + b*100 + j];
        }
        ws[i] = val;
    }
}

// ---------------- the fused 3-layer kernel ----------------
__global__ __launch_bounds__(256, 5) void k_fused(
    const float* __restrict__ node_pos, const float* __restrict__ bar,
    const float* __restrict__ Wemb, const float* __restrict__ b1,
    const float* __restrict__ Wout, const float* __restrict__ ws,
    float* __restrict__ out, W3J w3j)
{
    // 32.0 KB -> 5 blocks/CU (20 waves/CU)
    __shared__ __align__(16) float xs0[NE][450], xs1[NE][450];
    __shared__ __align__(16) float wls[NE][800];   // [v][16]: wls p=0..14; msg aliased to 0..8
    __shared__ __align__(16) float tgg[NE][100];   // union: t100 / gates
    __shared__ __align__(16) float ck[NE][180];
    __shared__ __align__(16) float shs[NE][9];
    __shared__ __align__(16) float embs[NE][12];   // 0..9 emb, 10..11 bar pair

    const int t = threadIdx.x;
    const int e0 = blockIdx.x * NE;

    constexpr int cL1[15]    = {0,0,0,1,1,1,1,1,1,2,2,2,2,2,2};
    constexpr int cCKOFF[15] = {0,1,4,9,18,21,30,45,54,69,94,109,134,139,154};
    constexpr int cSLO[3]    = {0,1,4};
    constexpr int cPBYL3[15] = {0,4,12, 1,3,5,7,10,13, 2,6,8,9,11,14};
    constexpr int cPL3S[4]   = {0,3,9,15};
    constexpr float cINVNP[3] = {0.57735026918962584f, 0.40824829046386302f, 0.40824829046386302f};

    const float* WP3 = ws + WS_WP3;
    const float* W6P = ws + WS_W6P;
    const float* W2T = ws + WS_W2T;
    const float* WGT = ws + WS_WGT;
    const float* W1T = ws + WS_W1T;

    // ---- Phase A: per-edge sh + radial embedding ----
    if (t < NE) {
        const int e = t;
        const float* np = node_pos + (size_t)(e0 + e) * 6;
        float vx = np[1] - np[0], vy = np[3] - np[2], vz = np[5] - np[4];
        float r = sqrtf(vx*vx + vy*vy + vz*vz);
        float inv = 1.0f / fmaxf(r, 1e-12f);
        float x = vx*inv, y = vy*inv, z = vz*inv;
        const float s3 = 1.7320508075688772f, s5 = 2.23606797749979f, s15 = 3.872983346207417f;
        shs[e][0] = 1.0f;
        shs[e][1] = s3*x; shs[e][2] = s3*y; shs[e][3] = s3*z;
        shs[e][4] = s15*x*z; shs[e][5] = s15*x*y;
        shs[e][6] = s5*(y*y - 0.5f*(x*x + z*z));
        shs[e][7] = s15*y*z;
        shs[e][8] = 0.5f*s15*(z*z - x*x);
        const float step = 4.0f / 11.0f;
        const float RC = (float)(1.14136 * 7.3890560989306495 * 3.1622776601683795);
        #pragma unroll
        for (int b = 0; b < 10; b++) {
            float center = step * (b + 1);
            float diff = (r - center) / step;
            float x1 = diff + 1.0f, x2 = 1.0f - diff;
            float u1 = (x1 > 0.0f) ? expf(-1.0f/x1) : 0.0f;
            float u2 = (x2 > 0.0f) ? expf(-1.0f/x2) : 0.0f;
            embs[e][b] = RC * u1 * u2;
        }
    }
    if (t >= 64 && t < 64 + 2*NE) {
        int q = t - 64;
        embs[q >> 1][10 + (q & 1)] = bar[2*e0 + q];
    }
    __syncthreads();

    // ---- Phase B: ck build + x init ----
    for (int idx = t; idx < NE*179; idx += 256) {
        int e = idx / 179, q = idx % 179;
        int p = 0; while (p < 14 && q >= d_CKOFFr[p+1]) p++;
        int rem = q - d_CKOFFr[p];
        int D2 = 2*d_L2r[p] + 1, D3 = 2*d_L3r[p] + 1;
        int i = rem / D3, k = rem % D3;
        const float* C = w3j.v + d_OFFr[p];
        const float* s = &shs[e][d_SLOr[d_L2r[p]]];
        float a = 0;
        for (int j = 0; j < D2; j++) a += C[(i*D2 + j)*D3 + k] * s[j];
        ck[e][q] = a;
    }
    for (int idx = t; idx < 2*NE*450; idx += 256) {
        int n = idx / 450, i = idx % 450;
        int e = n >> 1, half = n & 1;
        int u = i / 9, m = i % 9;
        float val = (m == 0) ? embs[e][10 + half] * Wemb[u] : 0.0f;
        if (half) xs1[e][i] = val; else xs0[e][i] = val;
    }
    __syncthreads();

    const bool act = (t < 50*NE);
    const int v = t / NE, ea = t % NE;

    // ================== 3 layers, all in LDS ==================
    for (int L = 0; L < 3; L++) {
        // ---- P1: t100 = gelu(emb@W1/sqrt(10) + b1) ----
        for (int idx = t; idx < NE*100; idx += 256) {
            int e = idx / 100, j = idx % 100;
            const float* wj = W1T + (L*100 + j)*12;
            float4 wa = *(const float4*)wj;
            float4 wb = *(const float4*)(wj + 4);
            float2 wc = *(const float2*)(wj + 8);
            float4 e0v = *(const float4*)&embs[e][0];
            float4 e1v = *(const float4*)&embs[e][4];
            float2 e2v = *(const float2*)&embs[e][8];
            float a = wa.x*e0v.x + wa.y*e0v.y + wa.z*e0v.z + wa.w*e0v.w
                    + wb.x*e1v.x + wb.y*e1v.y + wb.z*e1v.z + wb.w*e1v.w
                    + wc.x*e2v.x + wc.y*e2v.y;
            a = a * 0.31622776601683794f + b1[L*100 + j];
            float th = tanhf(0.7978845608028654f * (a + 0.044715f * a*a*a));
            tgg[e][j] = 0.5f * a * (1.0f + th);
        }
        __syncthreads();

        // ---- P2: wls = (t100 @ W2)/10, W2T float4 over j ----
        {
            const float* w2t = W2T + L*75000;
            const int o0 = t, o1 = t + 256;
            const bool has2 = (t < 238);
            const int o2 = has2 ? (t + 512) : 749;
            const float* p0 = w2t + o0*100;
            const float* p1 = w2t + o1*100;
            const float* p2 = w2t + o2*100;
            float a0[NE], a1[NE], a2[NE];
            #pragma unroll
            for (int e = 0; e < NE; e++) { a0[e] = 0; a1[e] = 0; a2[e] = 0; }
            for (int j = 0; j < 100; j += 4) {
                float4 w0 = *(const float4*)(p0 + j);
                float4 w1 = *(const float4*)(p1 + j);
                float4 w2v = *(const float4*)(p2 + j);
                #pragma unroll
                for (int e = 0; e < NE; e++) {
                    float4 tv = *(const float4*)&tgg[e][j];
                    a0[e] += w0.x*tv.x + w0.y*tv.y + w0.z*tv.z + w0.w*tv.w;
                    a1[e] += w1.x*tv.x + w1.y*tv.y + w1.z*tv.z + w1.w*tv.w;
                    a2[e] += w2v.x*tv.x + w2v.y*tv.y + w2v.z*tv.z + w2v.w*tv.w;
                }
            }
            #pragma unroll
            for (int e = 0; e < NE; e++) {
                { int vv = o0/15, pp = o0 - vv*15; wls[e][vv*16 + pp] = a0[e] * 0.1f; }
                { int vv = o1/15, pp = o1 - vv*15; wls[e][vv*16 + pp] = a1[e] * 0.1f; }
                if (has2) { int vv = o2/15, pp = o2 - vv*15; wls[e][vv*16 + pp] = a2[e] * 0.1f; }
            }
        }

        // ---- P3: three lmixes; packed weights, float2 LDS reads ----
        float hsc[9], n0r[9], n1r[9];
        #pragma unroll
        for (int m = 0; m < 9; m++) { hsc[m] = 0; n0r[m] = 0; n1r[m] = 0; }
        if (act) {
            const float* wp = WP3 + (size_t)(L*50 + v) * 400;  // [u][8]
            for (int u2 = 0; u2 < 50; u2 += 2) {
                float4 wa0 = *(const float4*)(wp + u2*8);       // wl0,wl1,wl2,ws0 (u2)
                float2 wa1 = *(const float2*)(wp + u2*8 + 4);   // ws1,ws2 (u2)
                float4 wb0 = *(const float4*)(wp + u2*8 + 8);   // u2+1
                float2 wb1 = *(const float2*)(wp + u2*8 + 12);
                float2 q[9];
                // xs0 block: 18 contiguous floats as 9 float2
                #pragma unroll
                for (int k = 0; k < 9; k++) q[k] = *(const float2*)&xs0[ea][u2*9 + 2*k];
                #pragma unroll
                for (int m = 0; m < 9; m++) {
                    const int l = (m == 0) ? 0 : ((m < 4) ? 1 : 2);
                    const float wlA = (l==0)?wa0.x:((l==1)?wa0.y:wa0.z);
                    const float wsA = (l==0)?wa0.w:((l==1)?wa1.x:wa1.y);
                    const float wlB = (l==0)?wb0.x:((l==1)?wb0.y:wb0.z);
                    const float wsB = (l==0)?wb0.w:((l==1)?wb1.x:wb1.y);
                    const int iA = m, iB = 9 + m;
                    const float xA = (iA & 1) ? q[iA>>1].y : q[iA>>1].x;
                    const float xB = (iB & 1) ? q[iB>>1].y : q[iB>>1].x;
                    hsc[m] += xA*wlA + xB*wlB;
                    n0r[m] += xA*wsA + xB*wsB;
                }
                // xs1 block
                #pragma unroll
                for (int k = 0; k < 9; k++) q[k] = *(const float2*)&xs1[ea][u2*9 + 2*k];
                #pragma unroll
                for (int m = 0; m < 9; m++) {
                    const int l = (m == 0) ? 0 : ((m < 4) ? 1 : 2);
                    const float wsA = (l==0)?wa0.w:((l==1)?wa1.x:wa1.y);
                    const float wsB = (l==0)?wb0.w:((l==1)?wb1.x:wb1.y);
                    const int iA = m, iB = 9 + m;
                    const float xA = (iA & 1) ? q[iA>>1].y : q[iA>>1].x;
                    const float xB = (iB & 1) ? q[iB>>1].y : q[iB>>1].x;
                    n1r[m] += xA*wsA + xB*wsB;
                }
            }
        }
        __syncthreads();   // xs reads done; wls (P2) settled
        if (act) {
            #pragma unroll
            for (int m = 0; m < 9; m++) {
                hsc[m] *= S_H;
                xs0[ea][v*9 + m] = n0r[m] * S_CS;
                xs1[ea][v*9 + m] = n1r[m] * S_CS;
            }
        }
        __syncthreads();

        // ---- P5: tensor-product messages; msg aliased into wls slots ----
        if (act) {
            float w[15];
            {
                float4 t0 = *(const float4*)&wls[ea][v*16];
                float4 t1 = *(const float4*)&wls[ea][v*16 + 4];
                float4 t2 = *(const float4*)&wls[ea][v*16 + 8];
                float4 t3 = *(const float4*)&wls[ea][v*16 + 12];  // .w = pad
                w[0]=t0.x; w[1]=t0.y; w[2]=t0.z; w[3]=t0.w;
                w[4]=t1.x; w[5]=t1.y; w[6]=t1.z; w[7]=t1.w;
                w[8]=t2.x; w[9]=t2.y; w[10]=t2.z; w[11]=t2.w;
                w[12]=t3.x; w[13]=t3.y; w[14]=t3.z;
            }
            float mg[9];
            #pragma unroll
            for (int k = 0; k < 9; ++k) {
                const int l3 = (k == 0) ? 0 : ((k < 4) ? 1 : 2);
                const int kl = k - cSLO[l3];
                float a = 0.f;
                #pragma unroll
                for (int pi = cPL3S[l3]; pi < cPL3S[l3+1]; ++pi) {
                    const int p = cPBYL3[pi];
                    const int l1 = cL1[p];
                    const int D1 = 2*l1 + 1, D3 = 2*l3 + 1;
                    float mm = 0.f;
                    #pragma unroll
                    for (int i = 0; i < D1; ++i)
                        mm += ck[ea][cCKOFF[p] + i*D3 + kl] * hsc[cSLO[l1] + i];
                    a += w[p] * mm;
                }
                mg[k] = a * cINVNP[l3];
            }
            *(float4*)&wls[ea][v*16]     = make_float4(mg[0], mg[1], mg[2], mg[3]);
            *(float4*)&wls[ea][v*16 + 4] = make_float4(mg[4], mg[5], mg[6], mg[7]);
            wls[ea][v*16 + 8] = mg[8];
        }
        __syncthreads();

        // ---- P6: xs1 += lmix(msg, Wlin2) * S_L2 ----
        if (act) {
            const float* w6 = W6P + (size_t)(L*50 + v) * 200;  // [u][4]
            float am[9];
            #pragma unroll
            for (int m = 0; m < 9; m++) am[m] = 0;
            for (int u = 0; u < 50; u++) {
                float4 wv = *(const float4*)(w6 + u*4);        // l0,l1,l2,pad
                float4 m0 = *(const float4*)&wls[ea][u*16];
                float4 m1 = *(const float4*)&wls[ea][u*16 + 4];
                float  m8 = wls[ea][u*16 + 8];
                am[0] += m0.x*wv.x;
                am[1] += m0.y*wv.y; am[2] += m0.z*wv.y; am[3] += m0.w*wv.y;
                am[4] += m1.x*wv.z; am[5] += m1.y*wv.z; am[6] += m1.z*wv.z; am[7] += m1.w*wv.z;
                am[8] += m8*wv.z;
            }
            #pragma unroll
            for (int m = 0; m < 9; m++) xs1[ea][v*9 + m] += am[m] * S_L2;
        }
        __syncthreads();

        // ---- P7: gate matmuls -> tgg ----
        if (act) {
            const float* wg = WGT + (L*50 + v) * 52;
            float a0 = 0, a1 = 0;
            #pragma unroll
            for (int u4 = 0; u4 < 48; u4 += 4) {
                float4 wv = *(const float4*)(wg + u4);
                a0 += xs0[ea][(u4+0)*9]*wv.x + xs0[ea][(u4+1)*9]*wv.y
                    + xs0[ea][(u4+2)*9]*wv.z + xs0[ea][(u4+3)*9]*wv.w;
                a1 += xs1[ea][(u4+0)*9]*wv.x + xs1[ea][(u4+1)*9]*wv.y
                    + xs1[ea][(u4+2)*9]*wv.z + xs1[ea][(u4+3)*9]*wv.w;
            }
            float2 wt = *(const float2*)(wg + 48);
            a0 += xs0[ea][48*9]*wt.x + xs0[ea][49*9]*wt.y;
            a1 += xs1[ea][48*9]*wt.x + xs1[ea][49*9]*wt.y;
            tgg[ea][v]      = sigf(a0 * S_H);
            tgg[ea][50 + v] = sigf(a1 * S_H);
        }
        __syncthreads();

        // ---- P8: apply gates in LDS ----
        for (int idx = t; idx < 2*NE*450; idx += 256) {
            int n = idx / 450, i = idx % 450;
            int e = n >> 1, half = n & 1;
            int u = i / 9, m = i % 9;
            float* xp = half ? &xs1[e][0] : &xs0[e][0];
            float val = xp[i];
            float g = tgg[e][half*50 + u];
            xp[i] = (m == 0) ? val * sigf(val) : val * g;
        }
        __syncthreads();
    }

    // ---- Output projection ----
    if (t < NE*6) {
        int e = t / 6, r = t % 6, half = r / 3, m = r % 3;
        const float* xp = half ? &xs1[e][0] : &xs0[e][0];
        float a = 0;
        #pragma unroll 2
        for (int u = 0; u < 50; ++u) a += xp[u*9 + 1 + m] * Wout[u];
        out[((size_t)(2*(e0 + e) + half))*3 + m] = a * S_H;
    }
}

// ---------------- launch ----------------
extern "C" void kernel_launch(void* const* d_in, const int* in_sizes, int n_in,
                              void* d_out, int out_size, void* d_ws, size_t ws_size,
                              hipStream_t stream) {
    const float* node_pos = (const float*)d_in[0];
    const float* bar      = (const float*)d_in[1];
    const float* Wemb     = (const float*)d_in[2];
    const float* Wsc      = (const float*)d_in[3];
    const float* Wlin1    = (const float*)d_in[4];
    const float* W1       = (const float*)d_in[5];
    const float* b1       = (const float*)d_in[6];
    const float* W2       = (const float*)d_in[7];
    const float* Wlin2    = (const float*)d_in[8];
    const float* Wgate    = (const float*)d_in[9];
    const float* Wout     = (const float*)d_in[10];
    float* out = (float*)d_out;
    float* ws  = (float*)d_ws;

    W3J w3j;
    build_w3j(w3j);

    k_pack<<<(WS_TOTAL + 255)/256, 256, 0, stream>>>(Wsc, Wlin1, Wlin2, Wgate, W2, W1, ws);
    k_fused<<<E_EDGES/NE, 256, 0, stream>>>(node_pos, bar, Wemb, b1, Wout, ws, out, w3j);
}

// Round 5
// 1243.428 us; speedup vs baseline: 2.2089x; 2.2089x over previous
//
#include <hip/hip_runtime.h>
#include <math.h>
#include <string.h>

// ---------------- problem constants ----------------
#define E_EDGES 40000
#define N_NODES 80000
#define NE 4          // edges per block

// ---- sign knobs (verified correct in round 1) ----
#define S111 1.0
#define S122 1.0
#define S212 1.0
#define S221 1.0
#define S222 1.0

struct W3J { float v[615]; };

// ---------------- host: build W3J tensors (verified round 1) ----------------
static void build_w3j(W3J& w) {
    const double s3 = sqrt(3.0), s5 = sqrt(5.0), s15 = sqrt(15.0);
    struct Mono { int a, b, c; double co; };
    Mono Y[3][5][3]; int nm[3][5];
    for (int l = 0; l < 3; l++) for (int c = 0; c < 5; c++) nm[l][c] = 0;
    nm[0][0] = 1; Y[0][0][0] = Mono{0,0,0,1.0};
    nm[1][0] = 1; Y[1][0][0] = Mono{1,0,0,s3};
    nm[1][1] = 1; Y[1][1][0] = Mono{0,1,0,s3};
    nm[1][2] = 1; Y[1][2][0] = Mono{0,0,1,s3};
    nm[2][0] = 1; Y[2][0][0] = Mono{1,0,1,s15};
    nm[2][1] = 1; Y[2][1][0] = Mono{1,1,0,s15};
    nm[2][2] = 3; Y[2][2][0] = Mono{0,2,0,s5};  Y[2][2][1] = Mono{2,0,0,-0.5*s5}; Y[2][2][2] = Mono{0,0,2,-0.5*s5};
    nm[2][3] = 1; Y[2][3][0] = Mono{0,1,1,s15};
    nm[2][4] = 2; Y[2][4][0] = Mono{0,0,2,0.5*s15}; Y[2][4][1] = Mono{2,0,0,-0.5*s15};

    static const int PL[15][3] = {{0,0,0},{0,1,1},{0,2,2},{1,0,1},{1,1,0},{1,1,1},{1,1,2},{1,2,1},
                                  {1,2,2},{2,0,2},{2,1,1},{2,1,2},{2,2,0},{2,2,1},{2,2,2}};
    static const int OFF[15]  = {0,1,10,35,44,53,80,125,170,245,270,315,390,415,490};
    static const int ANCH[15] = {0,0,0,0,0,5,22,22,29,0,22,9,0,13,2};
    const double ASGN[15] = {1,1,1,1,1, S111, 1,1, S122, 1,1, S212, 1, S221, S222};

    auto dfact = [](int n) { double r = 1.0; for (int k = n; k > 1; k -= 2) r *= k; return r; };

    double Mm[5][3][3]; memset(Mm, 0, sizeof(Mm));
    const double mh = s15 * 0.5;
    Mm[0][0][2] = Mm[0][2][0] = mh;
    Mm[1][0][1] = Mm[1][1][0] = mh;
    Mm[2][0][0] = -0.5*s5; Mm[2][1][1] = s5; Mm[2][2][2] = -0.5*s5;
    Mm[3][1][2] = Mm[3][2][1] = mh;
    Mm[4][0][0] = -mh; Mm[4][2][2] = mh;
    double T[3][5][5];
    for (int a = 0; a < 5; a++) for (int b = 0; b < 5; b++) {
        double K[3][3];
        for (int i = 0; i < 3; i++) for (int j = 0; j < 3; j++) {
            double ab = 0, ba = 0;
            for (int r = 0; r < 3; r++) { ab += Mm[a][i][r]*Mm[b][r][j]; ba += Mm[b][i][r]*Mm[a][r][j]; }
            K[i][j] = ab - ba;
        }
        T[0][a][b] = K[1][2]; T[1][a][b] = K[2][0]; T[2][a][b] = K[0][1];
    }

    for (int p = 0; p < 15; p++) {
        int l1 = PL[p][0], l2 = PL[p][1], l3 = PL[p][2];
        int d1 = 2*l1+1, d2 = 2*l2+1, d3 = 2*l3+1, d = d1*d2*d3;
        double tt[125];
        if (((l1 + l2 + l3) & 1) == 0) {
            for (int i = 0; i < d1; i++) for (int j = 0; j < d2; j++) for (int k = 0; k < d3; k++) {
                double a = 0;
                for (int q1 = 0; q1 < nm[l1][i]; q1++)
                for (int q2 = 0; q2 < nm[l2][j]; q2++)
                for (int q3 = 0; q3 < nm[l3][k]; q3++) {
                    const Mono& A = Y[l1][i][q1]; const Mono& B = Y[l2][j][q2]; const Mono& C = Y[l3][k][q3];
                    int xa = A.a+B.a+C.a, yb = A.b+B.b+C.b, zc = A.c+B.c+C.c;
                    if ((xa & 1) || (yb & 1) || (zc & 1)) continue;
                    a += A.co*B.co*C.co * dfact(xa-1)*dfact(yb-1)*dfact(zc-1) / dfact(xa+yb+zc+1);
                }
                tt[(i*d2 + j)*d3 + k] = a;
            }
        } else if (p == 5) {
            for (int q = 0; q < 27; q++) tt[q] = 0;
            tt[0*9+1*3+2] = 1; tt[1*9+2*3+0] = 1; tt[2*9+0*3+1] = 1;
            tt[0*9+2*3+1] = -1; tt[1*9+0*3+2] = -1; tt[2*9+1*3+0] = -1;
        } else {
            for (int q = 0; q < d; q++) tt[q] = 0;
            if (p == 8)  for (int i=0;i<3;i++) for(int a=0;a<5;a++) for(int b=0;b<5;b++) tt[(i*5+a)*5+b] = T[i][a][b];
            if (p == 11) for (int a=0;a<5;a++) for(int i=0;i<3;i++) for(int b=0;b<5;b++) tt[(a*3+i)*5+b] = T[i][a][b];
            if (p == 13) for (int a=0;a<5;a++) for(int b=0;b<5;b++) for(int i=0;i<3;i++) tt[(a*5+b)*3+i] = T[i][a][b];
        }
        double nrm = 0; for (int q = 0; q < d; q++) nrm += tt[q]*tt[q];
        nrm = sqrt(nrm);
        double sg = ((tt[ANCH[p]] >= 0) ? 1.0 : -1.0) * ASGN[p] / nrm;
        for (int q = 0; q < d; q++) w.v[OFF[p] + q] = (float)(tt[q] * sg);
    }
}

// ---------------- device tables (runtime-indexed, ck phase only) ----------------
__device__ const int d_L2r[15]    = {0,1,2,0,1,1,1,2,2,0,1,1,2,2,2};
__device__ const int d_L3r[15]    = {0,1,2,1,0,1,2,1,2,2,1,2,0,1,2};
__device__ const int d_OFFr[15]   = {0,1,10,35,44,53,80,125,170,245,270,315,390,415,490};
__device__ const int d_CKOFFr[15] = {0,1,4,9,18,21,30,45,54,69,94,109,134,139,154};
__device__ const int d_SLOr[3]    = {0,1,4};

#define S_H  0.1414213562373095f    // 1/sqrt(50)
#define S_CS 0.13065629648763766f   // cos(pi/8)/sqrt(50)
#define S_L2 0.03826834323650898f   // sin(pi/8)/10

// packed-weight layout in d_ws (floats)
#define WS_WP3 0         // [3][50][50][8] {wlin1 l0..2, wsc l0..2, pad, pad}  -> 60000
#define WS_W6P 60000     // [3][50][50][4] {wlin2 l0..2, pad}                  -> 30000
#define WS_WGT 90000     // [3][50][52]    Wgate transposed (pad 52)           -> 7800
#define WS_W1T 97800     // [3][100][12]   W1 transposed (pad 12)              -> 3600
#define WS_TOTAL 101400

__device__ __forceinline__ float sigf(float a) { return 1.0f / (1.0f + expf(-a)); }

// ---------------- one-time weight repack ----------------
__global__ void k_pack(const float* __restrict__ Wsc, const float* __restrict__ Wlin1,
                       const float* __restrict__ Wlin2, const float* __restrict__ Wgate,
                       const float* __restrict__ W1, float* __restrict__ ws) {
    for (int i = blockIdx.x*blockDim.x + threadIdx.x; i < WS_TOTAL; i += gridDim.x*blockDim.x) {
        float val = 0.0f;
        if (i < WS_W6P) {
            int c = i & 7, r = i >> 3; int u = r % 50, v = (r/50) % 50, L = r/2500;
            if (c < 3) val = Wlin1[L*7500 + c*2500 + u*50 + v];
            else if (c < 6) val = Wsc[L*7500 + (c-3)*2500 + u*50 + v];
        } else if (i < WS_WGT) {
            int q = i - WS_W6P; int c = q & 3, r = q >> 2; int u = r%50, v = (r/50)%50, L = r/2500;
            if (c < 3) val = Wlin2[L*7500 + c*2500 + u*50 + v];
        } else if (i < WS_W1T) {
            int q = i - WS_WGT; int u = q % 52, v = (q/52)%50, L = q/2600;
            if (u < 50) val = Wgate[L*2500 + u*50 + v];
        } else {
            int q = i - WS_W1T; int b = q % 12, j = (q/12)%100, L = q/1200;
            if (b < 10) val = W1[L*1000 + b*100 + j];
        }
        ws[i] = val;
    }
}

// ---------------- the fused 3-layer kernel ----------------
__global__ __launch_bounds__(256, 4) void k_fused(
    const float* __restrict__ node_pos, const float* __restrict__ bar,
    const float* __restrict__ Wemb, const float* __restrict__ b1,
    const float* __restrict__ W2, const float* __restrict__ Wout,
    const float* __restrict__ ws, float* __restrict__ out, W3J w3j)
{
    // 38.4 KB -> 4 blocks/CU (16 waves/CU)
    __shared__ __align__(16) float xs0[NE][450], xs1[NE][450], msg[NE][450];
    __shared__ __align__(16) float wls[NE][750];
    __shared__ __align__(16) float tgg[NE][100];   // union: t100 / gates
    __shared__ __align__(16) float ck[NE][180];
    __shared__ __align__(16) float shs[NE][9];
    __shared__ __align__(16) float embs[NE][12];   // 0..9 emb, 10..11 bar pair

    const int t = threadIdx.x;
    const int e0 = blockIdx.x * NE;

    constexpr int cL1[15]    = {0,0,0,1,1,1,1,1,1,2,2,2,2,2,2};
    constexpr int cCKOFF[15] = {0,1,4,9,18,21,30,45,54,69,94,109,134,139,154};
    constexpr int cSLO[3]    = {0,1,4};
    constexpr int cPBYL3[15] = {0,4,12, 1,3,5,7,10,13, 2,6,8,9,11,14};
    constexpr int cPL3S[4]   = {0,3,9,15};
    constexpr float cINVNP[3] = {0.57735026918962584f, 0.40824829046386302f, 0.40824829046386302f};

    const float* WP3 = ws + WS_WP3;
    const float* W6P = ws + WS_W6P;
    const float* WGT = ws + WS_WGT;
    const float* W1T = ws + WS_W1T;

    // ---- Phase A: per-edge sh + radial embedding ----
    if (t < NE) {
        const int e = t;
        const float* np = node_pos + (size_t)(e0 + e) * 6;
        float vx = np[1] - np[0], vy = np[3] - np[2], vz = np[5] - np[4];
        float r = sqrtf(vx*vx + vy*vy + vz*vz);
        float inv = 1.0f / fmaxf(r, 1e-12f);
        float x = vx*inv, y = vy*inv, z = vz*inv;
        const float s3 = 1.7320508075688772f, s5 = 2.23606797749979f, s15 = 3.872983346207417f;
        shs[e][0] = 1.0f;
        shs[e][1] = s3*x; shs[e][2] = s3*y; shs[e][3] = s3*z;
        shs[e][4] = s15*x*z; shs[e][5] = s15*x*y;
        shs[e][6] = s5*(y*y - 0.5f*(x*x + z*z));
        shs[e][7] = s15*y*z;
        shs[e][8] = 0.5f*s15*(z*z - x*x);
        const float step = 4.0f / 11.0f;
        const float RC = (float)(1.14136 * 7.3890560989306495 * 3.1622776601683795);
        #pragma unroll
        for (int b = 0; b < 10; b++) {
            float center = step * (b + 1);
            float diff = (r - center) / step;
            float x1 = diff + 1.0f, x2 = 1.0f - diff;
            float u1 = (x1 > 0.0f) ? expf(-1.0f/x1) : 0.0f;
            float u2 = (x2 > 0.0f) ? expf(-1.0f/x2) : 0.0f;
            embs[e][b] = RC * u1 * u2;
        }
    }
    if (t >= 64 && t < 64 + 2*NE) {
        int q = t - 64;
        embs[q >> 1][10 + (q & 1)] = bar[2*e0 + q];
    }
    __syncthreads();

    // ---- Phase B: ck build + x init ----
    for (int idx = t; idx < NE*179; idx += 256) {
        int e = idx / 179, q = idx % 179;
        int p = 0; while (p < 14 && q >= d_CKOFFr[p+1]) p++;
        int rem = q - d_CKOFFr[p];
        int D2 = 2*d_L2r[p] + 1, D3 = 2*d_L3r[p] + 1;
        int i = rem / D3, k = rem % D3;
        const float* C = w3j.v + d_OFFr[p];
        const float* s = &shs[e][d_SLOr[d_L2r[p]]];
        float a = 0;
        for (int j = 0; j < D2; j++) a += C[(i*D2 + j)*D3 + k] * s[j];
        ck[e][q] = a;
    }
    for (int idx = t; idx < 2*NE*450; idx += 256) {
        int n = idx / 450, i = idx % 450;
        int e = n >> 1, half = n & 1;
        int u = i / 9, m = i % 9;
        float val = (m == 0) ? embs[e][10 + half] * Wemb[u] : 0.0f;
        if (half) xs1[e][i] = val; else xs0[e][i] = val;
    }
    __syncthreads();

    const bool act = (t < 50*NE);
    const int v = t / NE, ea = t % NE;

    // ================== 3 layers, all in LDS ==================
    for (int L = 0; L < 3; L++) {
        // ---- P1: t100 = gelu(emb@W1/sqrt(10) + b1), W1T float4 ----
        for (int idx = t; idx < NE*100; idx += 256) {
            int e = idx / 100, j = idx % 100;
            const float* wj = W1T + (L*100 + j)*12;
            float4 wa = *(const float4*)wj;
            float4 wb = *(const float4*)(wj + 4);
            float2 wc = *(const float2*)(wj + 8);
            float4 e0v = *(const float4*)&embs[e][0];
            float4 e1v = *(const float4*)&embs[e][4];
            float2 e2v = *(const float2*)&embs[e][8];
            float a = wa.x*e0v.x + wa.y*e0v.y + wa.z*e0v.z + wa.w*e0v.w
                    + wb.x*e1v.x + wb.y*e1v.y + wb.z*e1v.z + wb.w*e1v.w
                    + wc.x*e2v.x + wc.y*e2v.y;
            a = a * 0.31622776601683794f + b1[L*100 + j];
            float th = tanhf(0.7978845608028654f * (a + 0.044715f * a*a*a));
            tgg[e][j] = 0.5f * a * (1.0f + th);
        }
        __syncthreads();

        // ---- P2: wls = (t100 @ W2)/10 — original W2 layout, coalesced rows ----
        {
            const float* W2L = W2 + L*75000;
            const int o0 = t, o1 = t + 256;
            const bool has2 = (t < 238);
            const int o2 = has2 ? (t + 512) : 749;
            float a0[NE], a1[NE], a2[NE];
            #pragma unroll
            for (int e = 0; e < NE; e++) { a0[e] = 0; a1[e] = 0; a2[e] = 0; }
            #pragma unroll 4
            for (int j = 0; j < 100; j++) {
                const float* W2j = W2L + j*750;
                float w0 = W2j[o0], w1 = W2j[o1], w2 = W2j[o2];
                #pragma unroll
                for (int e = 0; e < NE; e++) {
                    float tv = tgg[e][j];
                    a0[e] += w0 * tv; a1[e] += w1 * tv; a2[e] += w2 * tv;
                }
            }
            #pragma unroll
            for (int e = 0; e < NE; e++) {
                wls[e][o0] = a0[e] * 0.1f;
                wls[e][o1] = a1[e] * 0.1f;
                if (has2) wls[e][o2] = a2[e] * 0.1f;
            }
        }

        // ---- P3: three lmixes; packed weights (2 u / 4 loads), float2 xs reads ----
        float hsc[9], n0r[9], n1r[9];
        #pragma unroll
        for (int m = 0; m < 9; m++) { hsc[m] = 0; n0r[m] = 0; n1r[m] = 0; }
        if (act) {
            const float* wp = WP3 + (size_t)(L*50 + v) * 400;  // [u][8]
            for (int u2 = 0; u2 < 50; u2 += 2) {
                float4 wa0 = *(const float4*)(wp + u2*8);       // wl0,wl1,wl2,ws0 (u2)
                float2 wa1 = *(const float2*)(wp + u2*8 + 4);   // ws1,ws2 (u2)
                float4 wb0 = *(const float4*)(wp + u2*8 + 8);   // u2+1
                float2 wb1 = *(const float2*)(wp + u2*8 + 12);
                float2 q[9];
                #pragma unroll
                for (int k = 0; k < 9; k++) q[k] = *(const float2*)&xs0[ea][u2*9 + 2*k];
                #pragma unroll
                for (int m = 0; m < 9; m++) {
                    const int l = (m == 0) ? 0 : ((m < 4) ? 1 : 2);
                    const float wlA = (l==0)?wa0.x:((l==1)?wa0.y:wa0.z);
                    const float wsA = (l==0)?wa0.w:((l==1)?wa1.x:wa1.y);
                    const float wlB = (l==0)?wb0.x:((l==1)?wb0.y:wb0.z);
                    const float wsB = (l==0)?wb0.w:((l==1)?wb1.x:wb1.y);
                    const int iA = m, iB = 9 + m;
                    const float xA = (iA & 1) ? q[iA>>1].y : q[iA>>1].x;
                    const float xB = (iB & 1) ? q[iB>>1].y : q[iB>>1].x;
                    hsc[m] += xA*wlA + xB*wlB;
                    n0r[m] += xA*wsA + xB*wsB;
                }
                #pragma unroll
                for (int k = 0; k < 9; k++) q[k] = *(const float2*)&xs1[ea][u2*9 + 2*k];
                #pragma unroll
                for (int m = 0; m < 9; m++) {
                    const int l = (m == 0) ? 0 : ((m < 4) ? 1 : 2);
                    const float wsA = (l==0)?wa0.w:((l==1)?wa1.x:wa1.y);
                    const float wsB = (l==0)?wb0.w:((l==1)?wb1.x:wb1.y);
                    const int iA = m, iB = 9 + m;
                    const float xA = (iA & 1) ? q[iA>>1].y : q[iA>>1].x;
                    const float xB = (iB & 1) ? q[iB>>1].y : q[iB>>1].x;
                    n1r[m] += xA*wsA + xB*wsB;
                }
            }
        }
        __syncthreads();   // xs reads done; wls (P2) settled
        if (act) {
            #pragma unroll
            for (int m = 0; m < 9; m++) {
                hsc[m] *= S_H;
                xs0[ea][v*9 + m] = n0r[m] * S_CS;
                xs1[ea][v*9 + m] = n1r[m] * S_CS;
            }
        }
        __syncthreads();

        // ---- P5: tensor-product messages ----
        if (act) {
            float w[15];
            #pragma unroll
            for (int p = 0; p < 15; p++) w[p] = wls[ea][v*15 + p];
            float mg[9];
            #pragma unroll
            for (int k = 0; k < 9; ++k) {
                const int l3 = (k == 0) ? 0 : ((k < 4) ? 1 : 2);
                const int kl = k - cSLO[l3];
                float a = 0.f;
                #pragma unroll
                for (int pi = cPL3S[l3]; pi < cPL3S[l3+1]; ++pi) {
                    const int p = cPBYL3[pi];
                    const int l1 = cL1[p];
                    const int D1 = 2*l1 + 1, D3 = 2*l3 + 1;
                    float mm = 0.f;
                    #pragma unroll
                    for (int i = 0; i < D1; ++i)
                        mm += ck[ea][cCKOFF[p] + i*D3 + kl] * hsc[cSLO[l1] + i];
                    a += w[p] * mm;
                }
                mg[k] = a * cINVNP[l3];
            }
            #pragma unroll
            for (int k = 0; k < 9; ++k) msg[ea][v*9 + k] = mg[k];
        }
        __syncthreads();

        // ---- P6: xs1 += lmix(msg, Wlin2) * S_L2, packed W6P ----
        if (act) {
            const float* w6 = W6P + (size_t)(L*50 + v) * 200;  // [u][4]
            float am[9];
            #pragma unroll
            for (int m = 0; m < 9; m++) am[m] = 0;
            for (int u = 0; u < 50; u++) {
                float4 wv = *(const float4*)(w6 + u*4);        // l0,l1,l2,pad
                const float* mp = &msg[ea][u*9];
                am[0] += mp[0]*wv.x;
                am[1] += mp[1]*wv.y; am[2] += mp[2]*wv.y; am[3] += mp[3]*wv.y;
                am[4] += mp[4]*wv.z; am[5] += mp[5]*wv.z; am[6] += mp[6]*wv.z;
                am[7] += mp[7]*wv.z; am[8] += mp[8]*wv.z;
            }
            #pragma unroll
            for (int m = 0; m < 9; m++) xs1[ea][v*9 + m] += am[m] * S_L2;
        }
        __syncthreads();

        // ---- P7: gate matmuls -> tgg ----
        if (act) {
            const float* wg = WGT + (L*50 + v) * 52;
            float a0 = 0, a1 = 0;
            #pragma unroll
            for (int u4 = 0; u4 < 48; u4 += 4) {
                float4 wv = *(const float4*)(wg + u4);
                a0 += xs0[ea][(u4+0)*9]*wv.x + xs0[ea][(u4+1)*9]*wv.y
                    + xs0[ea][(u4+2)*9]*wv.z + xs0[ea][(u4+3)*9]*wv.w;
                a1 += xs1[ea][(u4+0)*9]*wv.x + xs1[ea][(u4+1)*9]*wv.y
                    + xs1[ea][(u4+2)*9]*wv.z + xs1[ea][(u4+3)*9]*wv.w;
            }
            float2 wt = *(const float2*)(wg + 48);
            a0 += xs0[ea][48*9]*wt.x + xs0[ea][49*9]*wt.y;
            a1 += xs1[ea][48*9]*wt.x + xs1[ea][49*9]*wt.y;
            tgg[ea][v]      = sigf(a0 * S_H);
            tgg[ea][50 + v] = sigf(a1 * S_H);
        }
        __syncthreads();

        // ---- P8: apply gates in LDS ----
        for (int idx = t; idx < 2*NE*450; idx += 256) {
            int n = idx / 450, i = idx % 450;
            int e = n >> 1, half = n & 1;
            int u = i / 9, m = i % 9;
            float* xp = half ? &xs1[e][0] : &xs0[e][0];
            float val = xp[i];
            float g = tgg[e][half*50 + u];
            xp[i] = (m == 0) ? val * sigf(val) : val * g;
        }
        __syncthreads();
    }

    // ---- Output projection ----
    if (t < NE*6) {
        int e = t / 6, r = t % 6, half = r / 3, m = r % 3;
        const float* xp = half ? &xs1[e][0] : &xs0[e][0];
        float a = 0;
        #pragma unroll 2
        for (int u = 0; u < 50; ++u) a += xp[u*9 + 1 + m] * Wout[u];
        out[((size_t)(2*(e0 + e) + half))*3 + m] = a * S_H;
    }
}

// ---------------- launch ----------------
extern "C" void kernel_launch(void* const* d_in, const int* in_sizes, int n_in,
                              void* d_out, int out_size, void* d_ws, size_t ws_size,
                              hipStream_t stream) {
    const float* node_pos = (const float*)d_in[0];
    const float* bar      = (const float*)d_in[1];
    const float* Wemb     = (const float*)d_in[2];
    const float* Wsc      = (const float*)d_in[3];
    const float* Wlin1    = (const float*)d_in[4];
    const float* W1       = (const float*)d_in[5];
    const float* b1       = (const float*)d_in[6];
    const float* W2       = (const float*)d_in[7];
    const float* Wlin2    = (const float*)d_in[8];
    const float* Wgate    = (const float*)d_in[9];
    const float* Wout     = (const float*)d_in[10];
    float* out = (float*)d_out;
    float* ws  = (float*)d_ws;

    W3J w3j;
    build_w3j(w3j);

    k_pack<<<(WS_TOTAL + 255)/256, 256, 0, stream>>>(Wsc, Wlin1, Wlin2, Wgate, W1, ws);
    k_fused<<<E_EDGES/NE, 256, 0, stream>>>(node_pos, bar, Wemb, b1, W2, Wout, ws, out, w3j);
}